// Round 8
// baseline (746.320 us; speedup 1.0000x reference)
//
#include <hip/hip_runtime.h>

#define B_ 4
#define S_ 1024
#define D_ 1024
#define H_ 16
#define DH_ 64
#define OOS 0.03125f   // 1/sqrt(1024)

// attn-consumable plane sizes (ushort elements)
#define QPL (1088 * 64)       // Qu/Qv: 1024 rows + 64 pad rows (garbage-ok)
#define KPL (1024 * 64)       // K swizzled
#define VPL (1024 * 64)       // V^T swizzled
#define PPL (200 * 1024)      // P swizzled: rows -1056..2143
#define PADLO 1056

// GEMM-operand swizzled planes: blocks of 16 rows x 32 k = 512 ushorts
#define APL_SW (256 * 32 * 512)   // 4096-row activations
#define WPL_SW (64 * 32 * 512)    // 1024-row weights

typedef __attribute__((ext_vector_type(8))) short short8;
typedef __attribute__((ext_vector_type(4))) float f32x4;
typedef const __attribute__((address_space(1))) unsigned int* gas_t;
typedef __attribute__((address_space(3))) unsigned int* las_t;

__device__ __forceinline__ ushort f2bf(float x) {
  unsigned u = __float_as_uint(x);
  unsigned r = u + 0x7fffu + ((u >> 16) & 1u);
  return (ushort)(r >> 16);
}
__device__ __forceinline__ float bf2f(ushort u) {
  return __uint_as_float(((unsigned)u) << 16);
}

union pack8 { ushort u[8]; uint4 v; };

// ---------------------------------------------------------------------------
// fp32 -> (hi, lo) bf16 split, written in GEMM-fragment-swizzled block layout.
// ---------------------------------------------------------------------------
struct ConvDesc { const float* src; ushort* hi; ushort* lo; };
struct ConvArgs { ConvDesc d[5]; };

__global__ __launch_bounds__(256) void conv_split(ConvArgs args)
{
  const ConvDesc dd = args.d[blockIdx.y];
  const int tt = blockIdx.x;
  const int tid = threadIdx.x;
  const float* src = dd.src + (size_t)tt * 16 * 1024;
  ushort* hi = dd.hi + (size_t)tt * 32 * 512;
  ushort* lo = dd.lo + (size_t)tt * 32 * 512;
#pragma unroll 4
  for (int q = 0; q < 16; ++q) {
    const int s = q * 256 + tid;
    const int r = s >> 8, c4 = s & 255;
    const float4 x = *(const float4*)(src + r * 1024 + c4 * 4);
    const int k = c4 * 4;
    const size_t addr = (size_t)(k >> 5) * 512 + ((k & 31) >> 3) * 128 + r * 8 + (k & 7);
    ushort4 hu, lu;
    hu.x = f2bf(x.x); lu.x = f2bf(x.x - bf2f(hu.x));
    hu.y = f2bf(x.y); lu.y = f2bf(x.y - bf2f(hu.y));
    hu.z = f2bf(x.z); lu.z = f2bf(x.z - bf2f(hu.z));
    hu.w = f2bf(x.w); lu.w = f2bf(x.w - bf2f(hu.w));
    *(ushort4*)(hi + addr) = hu;
    *(ushort4*)(lo + addr) = lu;
  }
}

// ---------------------------------------------------------------------------
// Fused QKVP bf16x3 MFMA GEMM with chunked XCD swizzle (T1). Round-6 version
// (single-buffered; the round-7 explicit dbuf was neutral -> reverted).
// Tile 128x128, BK=32, 4 waves as 2x2 of 64x64.
// ---------------------------------------------------------------------------
struct GemmDesc {
  const ushort* Ahi; const ushort* Alo;
  const ushort* Bhi; const ushort* Blo;
  const float* bias; ushort* O1; ushort* O2;
  const float* ub; const float* vb; int mode; int pad;
};
struct GemmArgs { GemmDesc g[4]; };

__global__ __launch_bounds__(256, 2) void gemm_fused(GemmArgs args)
{
  __shared__ __align__(16) ushort SM[16384];  // 32 KB staging; epilogue 2x16KB E
  // chunked XCD swizzle (nwg = 1024, divisible by 8 -> bijective)
  const int lid = blockIdx.x + 8 * blockIdx.y + 256 * blockIdx.z;
  const int swz = (lid & 7) * 128 + (lid >> 3);
  const int bx = swz & 7;
  const int by = (swz >> 3) & 31;
  const int bz = swz >> 8;

  const GemmDesc g = args.g[bz];
  const int tid = threadIdx.x;
  const int wave = tid >> 6, lane = tid & 63;
  const int m16 = lane & 15, quad = lane >> 4;
  const int mw2 = wave & 1, nw2 = wave >> 1;
  const int mt0 = by * 8;   // A t-tile base (16-row units)
  const int nt0 = bx * 8;   // B t-tile base

  f32x4 acc[4][4];
#pragma unroll
  for (int mf = 0; mf < 4; ++mf)
#pragma unroll
    for (int nf = 0; nf < 4; ++nf) acc[mf][nf] = (f32x4){0.f, 0.f, 0.f, 0.f};

  for (int kb = 0; kb < 32; ++kb) {
    __syncthreads();
    for (int t = wave; t < 32; t += 4) {
      const ushort* gp;
      int l;
      if (t < 8)       { gp = g.Ahi + ((size_t)(mt0 + t) * 32 + kb) * 512;       l = t * 512; }
      else if (t < 16) { gp = g.Alo + ((size_t)(mt0 + t - 8) * 32 + kb) * 512;   l = 4096 + (t - 8) * 512; }
      else if (t < 24) { gp = g.Bhi + ((size_t)(nt0 + t - 16) * 32 + kb) * 512;  l = 8192 + (t - 16) * 512; }
      else             { gp = g.Blo + ((size_t)(nt0 + t - 24) * 32 + kb) * 512;  l = 12288 + (t - 24) * 512; }
      __builtin_amdgcn_global_load_lds((gas_t)(gp + lane * 8), (las_t)(SM + l), 16, 0, 0);
    }
    __syncthreads();
    short8 ah[4], al[4], bh[4], bl[4];
#pragma unroll
    for (int mf = 0; mf < 4; ++mf) {
      ah[mf] = *(const short8*)(SM + (mw2 * 4 + mf) * 512 + lane * 8);
      al[mf] = *(const short8*)(SM + 4096 + (mw2 * 4 + mf) * 512 + lane * 8);
    }
#pragma unroll
    for (int nf = 0; nf < 4; ++nf) {
      bh[nf] = *(const short8*)(SM + 8192 + (nw2 * 4 + nf) * 512 + lane * 8);
      bl[nf] = *(const short8*)(SM + 12288 + (nw2 * 4 + nf) * 512 + lane * 8);
    }
#pragma unroll
    for (int mf = 0; mf < 4; ++mf)
#pragma unroll
      for (int nf = 0; nf < 4; ++nf) {
        acc[mf][nf] = __builtin_amdgcn_mfma_f32_16x16x32_bf16(ah[mf], bh[nf], acc[mf][nf], 0, 0, 0);
        acc[mf][nf] = __builtin_amdgcn_mfma_f32_16x16x32_bf16(ah[mf], bl[nf], acc[mf][nf], 0, 0, 0);
        acc[mf][nf] = __builtin_amdgcn_mfma_f32_16x16x32_bf16(al[mf], bh[nf], acc[mf][nf], 0, 0, 0);
      }
  }

  // ---- epilogue: 2 phases; phase p writes chunks (rows p*64) for both col
  //      halves into E0/E1 simultaneously (waves p and p+2), then all read.
  const int Mb = by * 128, Nb = bx * 128;
  float* const E0 = (float*)SM;
  float* const E1 = (float*)(SM + 8192);
#pragma unroll
  for (int p = 0; p < 2; ++p) {
    __syncthreads();
    if (mw2 == p) {
      float* const E = nw2 ? E1 : E0;
#pragma unroll
      for (int mf = 0; mf < 4; ++mf)
#pragma unroll
        for (int nf = 0; nf < 4; ++nf)
#pragma unroll
          for (int reg = 0; reg < 4; ++reg)
            E[(mf * 16 + quad * 4 + reg) * 64 + nf * 16 + m16] = acc[mf][nf][reg];
    }
    __syncthreads();

#pragma unroll
    for (int cpart = 0; cpart < 2; ++cpart) {
      float* const E = cpart ? E1 : E0;
      const int tokBase = Mb + p * 64;
      const int nBase = Nb + cpart * 64;

      if (g.mode == 3) {
#pragma unroll
        for (int q = 0; q < 2; ++q) {
          const int s = tid + 256 * q;
          const int cc = s & 63, rg = s >> 6;             // col, row-group of 8
          const int tok0 = tokBase + rg * 8;
          const int n = nBase + cc;
          const int bb = tok0 >> 10, jr = tok0 & 1023;
          const int jt = jr >> 6, ksj = (jr >> 5) & 1, qk = (jr >> 3) & 3;
          const int h = n >> 6, dd = n & 63;
          const int subd = dd >> 4, nn = dd & 15;
          const size_t base = (size_t)(bb * 16 + h) * VPL + (size_t)jt * 4096 +
                              (size_t)(subd * 2 + ksj) * 512 + (qk * 16 + nn) * 8;
          const float bvv = g.bias[n];
          pack8 pk;
#pragma unroll
          for (int i = 0; i < 8; ++i) pk.u[i] = f2bf(E[(rg * 8 + i) * 64 + cc] + bvv);
          *(uint4*)(g.O1 + base) = pk.v;
        }
      } else {
#pragma unroll
        for (int q = 0; q < 2; ++q) {
          const int s = tid + 256 * q;
          const int r = s >> 3, gc = s & 7;
          const int token = tokBase + r;
          const int n = nBase + gc * 8;
          float v[8];
          *(float4*)&v[0] = *(const float4*)&E[r * 64 + gc * 8];
          *(float4*)&v[4] = *(const float4*)&E[r * 64 + gc * 8 + 4];
          if (g.mode == 1) {
            const int bb = token >> 10, sr = token & 1023;
            const int h = n >> 6, d = n & 63;
            const size_t base = (size_t)(bb * 16 + h) * QPL + (size_t)sr * 64 + d;
            pack8 pu, pv;
#pragma unroll
            for (int j = 0; j < 8; ++j) {
              const float qv_ = v[j] + g.bias[n + j];
              pu.u[j] = f2bf(qv_ + g.ub[n + j]);
              pv.u[j] = f2bf(qv_ + g.vb[n + j]);
            }
            *(uint4*)(g.O1 + base) = pu.v;
            *(uint4*)(g.O2 + base) = pv.v;
          } else {  // mode 2 (Ksw, +bias) or 4 (Psw, no bias)
            const int bb = token >> 10, jr = token & 1023;
            const int h = n >> 6, dd = n & 63;
            const int ks = dd >> 5, qk = (dd >> 3) & 3;
            size_t base;
            if (g.mode == 2)
              base = (size_t)(bb * 16 + h) * KPL + (size_t)(jr >> 6) * 4096 +
                     (size_t)((((jr >> 4) & 3) * 2 + ks)) * 512 + (qk * 16 + (jr & 15)) * 8;
            else {
              const int ro = jr + PADLO;
              base = (size_t)(bb * 16 + h) * PPL + (size_t)(ro >> 4) * 1024 +
                     (size_t)ks * 512 + (qk * 16 + (ro & 15)) * 8;
            }
            pack8 pk;
#pragma unroll
            for (int j = 0; j < 8; ++j)
              pk.u[j] = f2bf(v[j] + (g.mode == 2 ? g.bias[n + j] : 0.f));
            *(uint4*)(g.O1 + base) = pk.v;
          }
        }
      }
    }
  }
}

// ---------------------------------------------------------------------------
// Output GEMM (round-2 proven structure): C[4096,1024] = A @ Wout^T + bout.
// ---------------------------------------------------------------------------
__global__ __launch_bounds__(256, 2) void gemm_out(
    const ushort* __restrict__ Ahi, const ushort* __restrict__ Alo,
    const ushort* __restrict__ Bhi, const ushort* __restrict__ Blo,
    const float* __restrict__ bias, float* __restrict__ C)
{
  __shared__ __align__(16) ushort SM[12288];  // 24 KB staging; epilogue 16 KB
  const int tid = threadIdx.x;
  const int wave = tid >> 6, lane = tid & 63;
  const int m16 = lane & 15, quad = lane >> 4;
  const int mw2 = wave & 1, nw2 = wave >> 1;
  const int mt0 = blockIdx.y * 4;
  const int nt0 = blockIdx.x * 8;

  f32x4 acc[2][4];
#pragma unroll
  for (int mf = 0; mf < 2; ++mf)
#pragma unroll
    for (int nf = 0; nf < 4; ++nf) acc[mf][nf] = (f32x4){0.f, 0.f, 0.f, 0.f};

  for (int kb = 0; kb < 32; ++kb) {
    __syncthreads();
    for (int t = wave; t < 24; t += 4) {
      const ushort* g;
      int l;
      if (t < 4)       { g = Ahi + ((size_t)(mt0 + t) * 32 + kb) * 512;      l = t * 512; }
      else if (t < 8)  { g = Alo + ((size_t)(mt0 + t - 4) * 32 + kb) * 512;  l = 2048 + (t - 4) * 512; }
      else if (t < 16) { g = Bhi + ((size_t)(nt0 + t - 8) * 32 + kb) * 512;  l = 4096 + (t - 8) * 512; }
      else             { g = Blo + ((size_t)(nt0 + t - 16) * 32 + kb) * 512; l = 8192 + (t - 16) * 512; }
      __builtin_amdgcn_global_load_lds((gas_t)(g + lane * 8), (las_t)(SM + l), 16, 0, 0);
    }
    __syncthreads();
    short8 ah[2], al[2], bh[4], bl[4];
#pragma unroll
    for (int mf = 0; mf < 2; ++mf) {
      ah[mf] = *(const short8*)(SM + (mw2 * 2 + mf) * 512 + lane * 8);
      al[mf] = *(const short8*)(SM + 2048 + (mw2 * 2 + mf) * 512 + lane * 8);
    }
#pragma unroll
    for (int nf = 0; nf < 4; ++nf) {
      bh[nf] = *(const short8*)(SM + 4096 + (nw2 * 4 + nf) * 512 + lane * 8);
      bl[nf] = *(const short8*)(SM + 8192 + (nw2 * 4 + nf) * 512 + lane * 8);
    }
#pragma unroll
    for (int mf = 0; mf < 2; ++mf)
#pragma unroll
      for (int nf = 0; nf < 4; ++nf) {
        acc[mf][nf] = __builtin_amdgcn_mfma_f32_16x16x32_bf16(ah[mf], bh[nf], acc[mf][nf], 0, 0, 0);
        acc[mf][nf] = __builtin_amdgcn_mfma_f32_16x16x32_bf16(ah[mf], bl[nf], acc[mf][nf], 0, 0, 0);
        acc[mf][nf] = __builtin_amdgcn_mfma_f32_16x16x32_bf16(al[mf], bh[nf], acc[mf][nf], 0, 0, 0);
      }
  }

  const int Mb = blockIdx.y * 64, Nb = blockIdx.x * 128;
  float* const E = (float*)SM;  // [64][64]
#pragma unroll
  for (int c = 0; c < 2; ++c) {
    __syncthreads();
    if (nw2 == c) {
#pragma unroll
      for (int mf = 0; mf < 2; ++mf)
#pragma unroll
        for (int nf = 0; nf < 4; ++nf)
#pragma unroll
          for (int reg = 0; reg < 4; ++reg)
            E[(mw2 * 32 + mf * 16 + quad * 4 + reg) * 64 + nf * 16 + m16] = acc[mf][nf][reg];
    }
    __syncthreads();
#pragma unroll
    for (int q = 0; q < 2; ++q) {
      const int s = tid + 256 * q;
      const int r = s >> 3, g = s & 7;
      const int token = Mb + r;
      const int n = Nb + c * 64 + g * 8;
      float v[8];
      *(float4*)&v[0] = *(const float4*)&E[r * 64 + g * 8];
      *(float4*)&v[4] = *(const float4*)&E[r * 64 + g * 8 + 4];
      float4 o0, o1;
      o0.x = v[0] + bias[n + 0]; o0.y = v[1] + bias[n + 1];
      o0.z = v[2] + bias[n + 2]; o0.w = v[3] + bias[n + 3];
      o1.x = v[4] + bias[n + 4]; o1.y = v[5] + bias[n + 5];
      o1.z = v[6] + bias[n + 6]; o1.w = v[7] + bias[n + 7];
      *(float4*)(C + (size_t)token * 1024 + n) = o0;
      *(float4*)(C + (size_t)token * 1024 + n + 4) = o1;
    }
  }
}

// ---------------------------------------------------------------------------
// len + zero P_sw row r=-1 (ro=1055: block 65, rr=15) per plane of this batch
// ---------------------------------------------------------------------------
__global__ void len_kernel(const int* __restrict__ mask, int* __restrict__ len,
                           ushort* __restrict__ Psw)
{
  const int b = blockIdx.x;
  int cnt = 0;
  for (int i = threadIdx.x; i < S_; i += 256)
    cnt += (mask[(size_t)b * S_ * S_ + (size_t)i * S_] != 0) ? 1 : 0;
  __shared__ int sh[256];
  sh[threadIdx.x] = cnt;
  __syncthreads();
  for (int off = 128; off > 0; off >>= 1) {
    if (threadIdx.x < off) sh[threadIdx.x] += sh[threadIdx.x + off];
    __syncthreads();
  }
  if (threadIdx.x == 0) len[b] = S_ - sh[0];
  for (int idx = threadIdx.x; idx < 16 * 64; idx += 256) {
    const int h = idx >> 6, d = idx & 63;
    Psw[(size_t)(b * 16 + h) * PPL + 65 * 1024 + (d >> 5) * 512 +
        (((d >> 3) & 3) * 16 + 15) * 8 + (d & 7)] = 0;
  }
}

// ---------------------------------------------------------------------------
// MFMA flash attention, 64 q-rows / block, 8 waves. NEW this round:
// V is NOT staged in LDS — each wave reads its 4 V fragments directly from
// global (same addresses staging used; 4x L2 reuse, plane is L2-resident).
// LDS drops 54.0 -> 44.8 KB => 3 blocks/CU (24 waves, was 16). Staged slots
// 52 -> 44 per iteration. Everything else identical to the verified round-4
// kernel.
// ---------------------------------------------------------------------------
__global__ __launch_bounds__(512, 4) void attn_mfma2(
    const ushort* __restrict__ Qu, const ushort* __restrict__ Qv,
    const ushort* __restrict__ Ksw, const ushort* __restrict__ Vsw,
    const ushort* __restrict__ Psw, const int* __restrict__ len,
    float* __restrict__ CTX)
{
  __shared__ __align__(16) ushort SMEM[22528];   // 45056 B
  __shared__ float mrow[64], lrow[64], arow[64];

  ushort* const Ks_  = SMEM;            // 8 slots (4096 us)
  ushort* const P1s_ = SMEM + 4096;     // 18 slots (9216 us) union window
  ushort* const P2s_ = SMEM + 13312;    // 18 slots
  float*  const sc   = (float*)(SMEM + 4096);   // 64x68 f32 = 17408 B (in P1s)
  ushort* const Pb   = SMEM + 13312;            // 64x72 us  =  9216 B (in P2s)

  const int tid  = threadIdx.x;
  const int wave = tid >> 6, lane = tid & 63;
  const int hw   = wave >> 2, w4 = wave & 3;   // half index, wave-within-half
  const int m16  = lane & 15, quad = lane >> 4;
  const int mw   = w4 & 1,  nw   = w4 >> 1;
  const int koff0 = quad * 8;

  const int base = blockIdx.x * 64;
  const int i0 = base + hw * 32;
  const int h  = blockIdx.y;
  const int b  = blockIdx.z;
  const int ph = b * 16 + h;
  const int L  = len[b];
  const size_t gb = ((size_t)b * S_) * D_ + h * DH_;

  if (base >= L) {
    for (int idx = tid; idx < 64 * 64; idx += 512) {
      const int r = idx >> 6, d = idx & 63;
      CTX[gb + (size_t)(base + r) * D_ + d] = 0.f;
    }
    return;
  }
  const bool active = (i0 < L);

  const ushort* quP = Qu + (size_t)ph * QPL;
  const ushort* qvP = Qv + (size_t)ph * QPL;
  short8 qufr[2][2], qvfr[2][2][2];
#pragma unroll
  for (int Mt = 0; Mt < 2; ++Mt)
#pragma unroll
    for (int ks = 0; ks < 2; ++ks) {
      qufr[Mt][ks] = *(const short8*)(quP + (size_t)(i0 + 16 * Mt + m16) * 64 + ks * 32 + koff0);
#pragma unroll
      for (int off = 0; off < 2; ++off)
        qvfr[off][Mt][ks] =
            *(const short8*)(qvP + (size_t)(i0 + off + 16 * Mt + m16) * 64 + ks * 32 + koff0);
    }

  if (tid < 64) { mrow[tid] = -3.0e38f; lrow[tid] = 0.f; arow[tid] = 0.f; }

  f32x4 ctx0 = {0.f, 0.f, 0.f, 0.f}, ctx1 = {0.f, 0.f, 0.f, 0.f};

  const ushort* ksP = Ksw + (size_t)ph * KPL;
  const ushort* vsP = Vsw + (size_t)ph * VPL;
  const ushort* psP = Psw + (size_t)ph * PPL;

  for (int j0 = 0; j0 < L; j0 += 64) {
    __syncthreads();

    const int jt = j0 >> 6;
    const int A1 = L - 32 - i0 + j0, A2 = j0 - i0 - 33;
    const int ro1 = A1 + PADLO, ro2 = A2 + PADLO;
    const int rb1 = ro1 >> 4, rb2 = ro2 >> 4;
    const int d1 = ro1 & 15, d2 = ro2 & 15;
    const int rb1lo = (L - 64 - base + j0 + PADLO) >> 4;
    const int rb2lo = (j0 - base - 65 + PADLO) >> 4;
    const ushort* P1h = P1s_ + ((rb1 - rb1lo) << 10);
    const ushort* P2h = P2s_ + ((rb2 - rb2lo) << 10);

    {
      const ushort* kgo = ksP + (size_t)jt * 4096;
      const ushort* p1o = psP + (size_t)rb1lo * 1024;
      const ushort* p2o = psP + (size_t)rb2lo * 1024;
      for (int t = wave; t < 44; t += 8) {
        const ushort* g;
        int l;
        if (t < 8)       { g = kgo + t * 512;        l = t * 512; }
        else if (t < 26) { g = p1o + (t - 8) * 512;  l = 4096 + (t - 8) * 512; }
        else             { g = p2o + (t - 26) * 512; l = 13312 + (t - 26) * 512; }
        __builtin_amdgcn_global_load_lds((gas_t)(g + lane * 8), (las_t)(SMEM + l), 16, 0, 0);
      }
    }
    // V fragments direct from global (issued before the drain barrier; land
    // alongside the staging). Same addresses staging used to fill Vts_.
    short8 vreg0, vreg1, vreg2, vreg3;
    {
      const ushort* vgo = vsP + (size_t)jt * 4096 + lane * 8;
      vreg0 = *(const short8*)(vgo + ((nw * 2) * 2 + 0) * 512);
      vreg1 = *(const short8*)(vgo + ((nw * 2) * 2 + 1) * 512);
      vreg2 = *(const short8*)(vgo + ((nw * 2 + 1) * 2 + 0) * 512);
      vreg3 = *(const short8*)(vgo + ((nw * 2 + 1) * 2 + 1) * 512);
    }
    __syncthreads();

    const int jrem = L - j0;
    const int jmax = (jrem < 64) ? jrem : 64;
    const int cthr = 31 + i0 - j0;

    f32x4 av[9];
#pragma unroll
    for (int t = 0; t < 9; ++t) {
      const int id = w4 + 4 * t;
      f32x4 a = {0.f, 0.f, 0.f, 0.f};
      if (active) {
        if (id < 8) {
          const int Mt = id & 1, Nt = id >> 1;
          if (16 * Nt < jmax) {
            const ushort* bp = Ks_ + (Nt * 2) * 512 + lane * 8;
            a = __builtin_amdgcn_mfma_f32_16x16x32_bf16(qufr[Mt][0], *(const short8*)bp, a, 0, 0, 0);
            a = __builtin_amdgcn_mfma_f32_16x16x32_bf16(qufr[Mt][1], *(const short8*)(bp + 512), a, 0, 0, 0);
          }
        } else if (id < 22) {
          const int e = id - 8, Mt = e & 1, Ntp = e >> 1;
          const int sm = 16 * (Ntp + Mt);
          if (sm >= d1 + 1 && sm <= jmax + d1 + 30 && 16 * Ntp - d1 <= cthr) {
            const ushort* bp = P1h + (Ntp * 2) * 512 + lane * 8;
            a = __builtin_amdgcn_mfma_f32_16x16x32_bf16(qvfr[0][Mt][0], *(const short8*)bp, a, 0, 0, 0);
            a = __builtin_amdgcn_mfma_f32_16x16x32_bf16(qvfr[0][Mt][1], *(const short8*)(bp + 512), a, 0, 0, 0);
          }
        } else {
          const int e = id - 22, Mt = e & 1, Ntp = e >> 1;
          const int sm = 16 * (Ntp + Mt);
          if (sm >= d2 + 1 && sm <= jmax + d2 + 30 && 16 * Ntp + 15 - d2 > cthr) {
            const ushort* bp = P2h + (Ntp * 2) * 512 + lane * 8;
            a = __builtin_amdgcn_mfma_f32_16x16x32_bf16(qvfr[1][Mt][0], *(const short8*)bp, a, 0, 0, 0);
            a = __builtin_amdgcn_mfma_f32_16x16x32_bf16(qvfr[1][Mt][1], *(const short8*)(bp + 512), a, 0, 0, 0);
          }
        }
      }
      av[t] = a;
    }
    __syncthreads();

#pragma unroll
    for (int t = 0; t < 2; ++t) {   // only t=0,1 can have id<8
      const int id = w4 + 4 * t;
      if (id < 8) {
        const int Mt = id & 1, Nt = id >> 1;
        if (16 * Nt < jmax) {
#pragma unroll
          for (int reg = 0; reg < 4; ++reg)
            sc[(hw * 32 + 16 * Mt + quad * 4 + reg) * 68 + 16 * Nt + m16] =
                active ? av[t][reg] : 0.f;
        }
      }
    }
    __syncthreads();

    if (active) {
#pragma unroll
      for (int t = 0; t < 9; ++t) {
        const int id = w4 + 4 * t;
        if (id >= 8) {
          const bool isG2 = id >= 22;
          const int e = id - (isG2 ? 22 : 8), Mt = e & 1, Ntp = e >> 1;
          const int dl = isG2 ? d2 : d1;
          const int sm = 16 * (Ntp + Mt);
          const bool use = sm >= dl + 1 && sm <= jmax + dl + 30 &&
                           (isG2 ? (16 * Ntp + 15 - dl > cthr) : (16 * Ntp - dl <= cthr));
          if (use) {
            const int c = 16 * Ntp + m16 - dl;
            const bool sel = isG2 ? (c > cthr) : (c <= cthr);
            if (sel) {
#pragma unroll
              for (int reg = 0; reg < 4; ++reg) {
                const int il = 16 * Mt + quad * 4 + reg;
                const int jl = c - 31 + il;
                if (jl >= 0 && jl < 64) sc[(hw * 32 + il) * 68 + jl] += av[t][reg];
              }
            }
          }
        }
      }
    }
    __syncthreads();

    {
      const int row = tid >> 3, t8 = tid & 7, jb = t8 * 8;
      const float* sr = sc + row * 68 + jb;
      float mx = -3.0e38f;
#pragma unroll
      for (int q = 0; q < 8; ++q)
        if (jb + q < jmax) mx = fmaxf(mx, sr[q]);
#pragma unroll
      for (int off = 1; off < 8; off <<= 1)
        mx = fmaxf(mx, __shfl_xor(mx, off, 64));
      if (t8 == 0) {
        const float mo = mrow[row];
        const float mn = fmaxf(mo, mx);
        arow[row] = __expf((mo - mn) * OOS);
        mrow[row] = mn;
      }
    }
    __syncthreads();
    {
      const int row = tid >> 3, t8 = tid & 7, jb = t8 * 8;
      const float m = mrow[row];
      const float* sr = sc + row * 68 + jb;
      float e[8], s = 0.f;
#pragma unroll
      for (int q = 0; q < 8; ++q) {
        float v = 0.f;
        if (jb + q < jmax) v = __expf((sr[q] - m) * OOS);
        e[q] = v;
        s += v;
      }
      ushort4 u0, u1;
      u0.x = f2bf(e[0]); u0.y = f2bf(e[1]); u0.z = f2bf(e[2]); u0.w = f2bf(e[3]);
      u1.x = f2bf(e[4]); u1.y = f2bf(e[5]); u1.z = f2bf(e[6]); u1.w = f2bf(e[7]);
      *(ushort4*)&Pb[row * 72 + jb] = u0;
      *(ushort4*)&Pb[row * 72 + jb + 4] = u1;
#pragma unroll
      for (int off = 1; off < 8; off <<= 1) s += __shfl_xor(s, off, 64);
      if (t8 == 0) lrow[row] = lrow[row] * arow[row] + s;
    }
    __syncthreads();

    if (active) {
      float al[4];
#pragma unroll
      for (int reg = 0; reg < 4; ++reg) al[reg] = arow[hw * 32 + 16 * mw + quad * 4 + reg];
#pragma unroll
      for (int reg = 0; reg < 4; ++reg) { ctx0[reg] *= al[reg]; ctx1[reg] *= al[reg]; }
      const ushort* ap = Pb + (hw * 32 + 16 * mw + m16) * 72;
      const short8 a0 = *(const short8*)(ap + koff0);
      const short8 a1 = *(const short8*)(ap + 32 + koff0);
      ctx0 = __builtin_amdgcn_mfma_f32_16x16x32_bf16(a0, vreg0, ctx0, 0, 0, 0);
      ctx0 = __builtin_amdgcn_mfma_f32_16x16x32_bf16(a1, vreg1, ctx0, 0, 0, 0);
      ctx1 = __builtin_amdgcn_mfma_f32_16x16x32_bf16(a0, vreg2, ctx1, 0, 0, 0);
      ctx1 = __builtin_amdgcn_mfma_f32_16x16x32_bf16(a1, vreg3, ctx1, 0, 0, 0);
    }
  }

#pragma unroll
  for (int reg = 0; reg < 4; ++reg) {
    const int il = 16 * mw + quad * 4 + reg;
    const int gi = i0 + il;
    const float inv = (active && gi < L) ? (1.f / lrow[hw * 32 + il]) : 0.f;
    CTX[gb + (size_t)gi * D_ + nw * 32 + m16]      = ctx0[reg] * inv;
    CTX[gb + (size_t)gi * D_ + nw * 32 + 16 + m16] = ctx1[reg] * inv;
  }
}

// ---------------------------------------------------------------------------
extern "C" void kernel_launch(void* const* d_in, const int* in_sizes, int n_in,
                              void* d_out, int out_size, void* d_ws, size_t ws_size,
                              hipStream_t stream)
{
  (void)in_sizes; (void)n_in; (void)out_size;
  const float* query = (const float*)d_in[0];
  const float* key   = (const float*)d_in[1];
  const float* value = (const float*)d_in[2];
  const float* pos   = (const float*)d_in[3];
  const float* Wq    = (const float*)d_in[4];
  const float* bq    = (const float*)d_in[5];
  const float* Wk    = (const float*)d_in[6];
  const float* bk    = (const float*)d_in[7];
  const float* Wv    = (const float*)d_in[8];
  const float* bv    = (const float*)d_in[9];
  const float* Wpos  = (const float*)d_in[10];
  const float* ub    = (const float*)d_in[11];
  const float* vb    = (const float*)d_in[12];
  const float* Wout  = (const float*)d_in[13];
  const float* bout  = (const float*)d_in[14];
  const int*   mask  = (const int*)d_in[15];

  char* cur = (char*)d_ws;
  auto take = [&](size_t bytes) {
    char* p = cur;
    cur += (bytes + 255) & ~(size_t)255;
    return p;
  };
  float*  CTX = (float*)take((size_t)4096 * 1024 * 4);
  ushort* Qu  = (ushort*)take((size_t)64 * QPL * 2);
  ushort* Qv  = (ushort*)take((size_t)64 * QPL * 2);
  ushort* Ksw = (ushort*)take((size_t)64 * KPL * 2);
  ushort* Vsw = (ushort*)take((size_t)64 * VPL * 2);
  ushort* Psw = (ushort*)take((size_t)64 * PPL * 2);
  ushort* Ah[4], *Al[4];
  for (int i = 0; i < 4; ++i) {
    Ah[i] = (ushort*)take((size_t)APL_SW * 2);
    Al[i] = (ushort*)take((size_t)APL_SW * 2);
  }
  ushort* Wh[5], *Wl[5];
  for (int i = 0; i < 5; ++i) {
    Wh[i] = (ushort*)take((size_t)WPL_SW * 2);
    Wl[i] = (ushort*)take((size_t)WPL_SW * 2);
  }
  int* len = (int*)take(256);
  // CTX hi/lo alias the (then-dead) query activation planes
  ushort* Ch = Ah[0];
  ushort* Cl = Al[0];
  if (ws_size < (size_t)(cur - (char*)d_ws)) return;

  len_kernel<<<dim3(B_), dim3(256), 0, stream>>>(mask, len, Psw);

  // fp32 -> swizzled hi/lo bf16 conversions
  {
    ConvArgs a;
    a.d[0] = {query, Ah[0], Al[0]};
    a.d[1] = {key,   Ah[1], Al[1]};
    a.d[2] = {value, Ah[2], Al[2]};
    a.d[3] = {pos,   Ah[3], Al[3]};
    a.d[4] = {query, Ah[0], Al[0]};  // unused
    conv_split<<<dim3(256, 4), dim3(256), 0, stream>>>(a);
    ConvArgs w;
    w.d[0] = {Wq,   Wh[0], Wl[0]};
    w.d[1] = {Wk,   Wh[1], Wl[1]};
    w.d[2] = {Wv,   Wh[2], Wl[2]};
    w.d[3] = {Wpos, Wh[3], Wl[3]};
    w.d[4] = {Wout, Wh[4], Wl[4]};
    conv_split<<<dim3(64, 5), dim3(256), 0, stream>>>(w);
  }

  // fused QKVP projections: z = {Q->Qu/Qv, K->Ksw, V->Vsw, P->Psw}
  {
    GemmArgs ga;
    ga.g[0] = {Ah[0], Al[0], Wh[0], Wl[0], bq, Qu, Qv, ub, vb, 1, 0};
    ga.g[1] = {Ah[1], Al[1], Wh[1], Wl[1], bk, Ksw, nullptr, nullptr, nullptr, 2, 0};
    ga.g[2] = {Ah[2], Al[2], Wh[2], Wl[2], bv, Vsw, nullptr, nullptr, nullptr, 3, 0};
    ga.g[3] = {Ah[3], Al[3], Wh[3], Wl[3], nullptr, Psw, nullptr, nullptr, nullptr, 4, 0};
    gemm_fused<<<dim3(8, 32, 4), dim3(256), 0, stream>>>(ga);
  }

  attn_mfma2<<<dim3(S_ / 64, H_, B_), dim3(512), 0, stream>>>(
      Qu, Qv, Ksw, Vsw, Psw, len, CTX);

  {
    ConvArgs c;
    c.d[0] = {CTX, Ch, Cl};
    c.d[1] = c.d[0]; c.d[2] = c.d[0]; c.d[3] = c.d[0]; c.d[4] = c.d[0];
    conv_split<<<dim3(256, 1), dim3(256), 0, stream>>>(c);
  }

  gemm_out<<<dim3(8, 64), dim3(256), 0, stream>>>(Ch, Cl, Wh[4], Wl[4], bout,
                                                  (float*)d_out);
}

// Round 9
// 633.936 us; speedup vs baseline: 1.1773x; 1.1773x over previous
//
#include <hip/hip_runtime.h>

#define B_ 4
#define S_ 1024
#define D_ 1024
#define H_ 16
#define DH_ 64
#define OOS 0.03125f   // 1/sqrt(1024)

// attn-consumable plane sizes (ushort elements)
#define QPL (1088 * 64)       // Qu/Qv: 1024 rows + 64 pad rows (garbage-ok)
#define KPL (1024 * 64)       // K swizzled
#define VPL (1024 * 64)       // V^T swizzled
#define PPL (200 * 1024)      // P swizzled: rows -1056..2143
#define PADLO 1056

// GEMM-operand swizzled planes: blocks of 16 rows x 32 k = 512 ushorts
#define APL_SW (256 * 32 * 512)   // 4096-row activations
#define WPL_SW (64 * 32 * 512)    // 1024-row weights

typedef __attribute__((ext_vector_type(8))) short short8;
typedef __attribute__((ext_vector_type(4))) float f32x4;
typedef const __attribute__((address_space(1))) unsigned int* gas_t;
typedef __attribute__((address_space(3))) unsigned int* las_t;

__device__ __forceinline__ ushort f2bf(float x) {
  unsigned u = __float_as_uint(x);
  unsigned r = u + 0x7fffu + ((u >> 16) & 1u);
  return (ushort)(r >> 16);
}
__device__ __forceinline__ float bf2f(ushort u) {
  return __uint_as_float(((unsigned)u) << 16);
}

union pack8 { ushort u[8]; uint4 v; };

// ---------------------------------------------------------------------------
// fp32 -> (hi, lo) bf16 split, written in GEMM-fragment-swizzled block layout.
// ---------------------------------------------------------------------------
struct ConvDesc { const float* src; ushort* hi; ushort* lo; };
struct ConvArgs { ConvDesc d[5]; };

__global__ __launch_bounds__(256) void conv_split(ConvArgs args)
{
  const ConvDesc dd = args.d[blockIdx.y];
  const int tt = blockIdx.x;
  const int tid = threadIdx.x;
  const float* src = dd.src + (size_t)tt * 16 * 1024;
  ushort* hi = dd.hi + (size_t)tt * 32 * 512;
  ushort* lo = dd.lo + (size_t)tt * 32 * 512;
#pragma unroll 4
  for (int q = 0; q < 16; ++q) {
    const int s = q * 256 + tid;
    const int r = s >> 8, c4 = s & 255;
    const float4 x = *(const float4*)(src + r * 1024 + c4 * 4);
    const int k = c4 * 4;
    const size_t addr = (size_t)(k >> 5) * 512 + ((k & 31) >> 3) * 128 + r * 8 + (k & 7);
    ushort4 hu, lu;
    hu.x = f2bf(x.x); lu.x = f2bf(x.x - bf2f(hu.x));
    hu.y = f2bf(x.y); lu.y = f2bf(x.y - bf2f(hu.y));
    hu.z = f2bf(x.z); lu.z = f2bf(x.z - bf2f(hu.z));
    hu.w = f2bf(x.w); lu.w = f2bf(x.w - bf2f(hu.w));
    *(ushort4*)(hi + addr) = hu;
    *(ushort4*)(lo + addr) = lu;
  }
}

// ---------------------------------------------------------------------------
// Fused QKVP bf16x3 MFMA GEMM with chunked XCD swizzle (T1). Round-6 version.
// Tile 128x128, BK=32, 4 waves as 2x2 of 64x64.
// ---------------------------------------------------------------------------
struct GemmDesc {
  const ushort* Ahi; const ushort* Alo;
  const ushort* Bhi; const ushort* Blo;
  const float* bias; ushort* O1; ushort* O2;
  const float* ub; const float* vb; int mode; int pad;
};
struct GemmArgs { GemmDesc g[4]; };

__global__ __launch_bounds__(256, 2) void gemm_fused(GemmArgs args)
{
  __shared__ __align__(16) ushort SM[16384];  // 32 KB staging; epilogue 2x16KB E
  // chunked XCD swizzle (nwg = 1024, divisible by 8 -> bijective)
  const int lid = blockIdx.x + 8 * blockIdx.y + 256 * blockIdx.z;
  const int swz = (lid & 7) * 128 + (lid >> 3);
  const int bx = swz & 7;
  const int by = (swz >> 3) & 31;
  const int bz = swz >> 8;

  const GemmDesc g = args.g[bz];
  const int tid = threadIdx.x;
  const int wave = tid >> 6, lane = tid & 63;
  const int m16 = lane & 15, quad = lane >> 4;
  const int mw2 = wave & 1, nw2 = wave >> 1;
  const int mt0 = by * 8;   // A t-tile base (16-row units)
  const int nt0 = bx * 8;   // B t-tile base

  f32x4 acc[4][4];
#pragma unroll
  for (int mf = 0; mf < 4; ++mf)
#pragma unroll
    for (int nf = 0; nf < 4; ++nf) acc[mf][nf] = (f32x4){0.f, 0.f, 0.f, 0.f};

  for (int kb = 0; kb < 32; ++kb) {
    __syncthreads();
    for (int t = wave; t < 32; t += 4) {
      const ushort* gp;
      int l;
      if (t < 8)       { gp = g.Ahi + ((size_t)(mt0 + t) * 32 + kb) * 512;       l = t * 512; }
      else if (t < 16) { gp = g.Alo + ((size_t)(mt0 + t - 8) * 32 + kb) * 512;   l = 4096 + (t - 8) * 512; }
      else if (t < 24) { gp = g.Bhi + ((size_t)(nt0 + t - 16) * 32 + kb) * 512;  l = 8192 + (t - 16) * 512; }
      else             { gp = g.Blo + ((size_t)(nt0 + t - 24) * 32 + kb) * 512;  l = 12288 + (t - 24) * 512; }
      __builtin_amdgcn_global_load_lds((gas_t)(gp + lane * 8), (las_t)(SM + l), 16, 0, 0);
    }
    __syncthreads();
    short8 ah[4], al[4], bh[4], bl[4];
#pragma unroll
    for (int mf = 0; mf < 4; ++mf) {
      ah[mf] = *(const short8*)(SM + (mw2 * 4 + mf) * 512 + lane * 8);
      al[mf] = *(const short8*)(SM + 4096 + (mw2 * 4 + mf) * 512 + lane * 8);
    }
#pragma unroll
    for (int nf = 0; nf < 4; ++nf) {
      bh[nf] = *(const short8*)(SM + 8192 + (nw2 * 4 + nf) * 512 + lane * 8);
      bl[nf] = *(const short8*)(SM + 12288 + (nw2 * 4 + nf) * 512 + lane * 8);
    }
#pragma unroll
    for (int mf = 0; mf < 4; ++mf)
#pragma unroll
      for (int nf = 0; nf < 4; ++nf) {
        acc[mf][nf] = __builtin_amdgcn_mfma_f32_16x16x32_bf16(ah[mf], bh[nf], acc[mf][nf], 0, 0, 0);
        acc[mf][nf] = __builtin_amdgcn_mfma_f32_16x16x32_bf16(ah[mf], bl[nf], acc[mf][nf], 0, 0, 0);
        acc[mf][nf] = __builtin_amdgcn_mfma_f32_16x16x32_bf16(al[mf], bh[nf], acc[mf][nf], 0, 0, 0);
      }
  }

  // ---- epilogue: 2 phases; phase p writes chunks (rows p*64) for both col
  //      halves into E0/E1 simultaneously (waves p and p+2), then all read.
  const int Mb = by * 128, Nb = bx * 128;
  float* const E0 = (float*)SM;
  float* const E1 = (float*)(SM + 8192);
#pragma unroll
  for (int p = 0; p < 2; ++p) {
    __syncthreads();
    if (mw2 == p) {
      float* const E = nw2 ? E1 : E0;
#pragma unroll
      for (int mf = 0; mf < 4; ++mf)
#pragma unroll
        for (int nf = 0; nf < 4; ++nf)
#pragma unroll
          for (int reg = 0; reg < 4; ++reg)
            E[(mf * 16 + quad * 4 + reg) * 64 + nf * 16 + m16] = acc[mf][nf][reg];
    }
    __syncthreads();

#pragma unroll
    for (int cpart = 0; cpart < 2; ++cpart) {
      float* const E = cpart ? E1 : E0;
      const int tokBase = Mb + p * 64;
      const int nBase = Nb + cpart * 64;

      if (g.mode == 3) {
#pragma unroll
        for (int q = 0; q < 2; ++q) {
          const int s = tid + 256 * q;
          const int cc = s & 63, rg = s >> 6;             // col, row-group of 8
          const int tok0 = tokBase + rg * 8;
          const int n = nBase + cc;
          const int bb = tok0 >> 10, jr = tok0 & 1023;
          const int jt = jr >> 6, ksj = (jr >> 5) & 1, qk = (jr >> 3) & 3;
          const int h = n >> 6, dd = n & 63;
          const int subd = dd >> 4, nn = dd & 15;
          const size_t base = (size_t)(bb * 16 + h) * VPL + (size_t)jt * 4096 +
                              (size_t)(subd * 2 + ksj) * 512 + (qk * 16 + nn) * 8;
          const float bvv = g.bias[n];
          pack8 pk;
#pragma unroll
          for (int i = 0; i < 8; ++i) pk.u[i] = f2bf(E[(rg * 8 + i) * 64 + cc] + bvv);
          *(uint4*)(g.O1 + base) = pk.v;
        }
      } else {
#pragma unroll
        for (int q = 0; q < 2; ++q) {
          const int s = tid + 256 * q;
          const int r = s >> 3, gc = s & 7;
          const int token = tokBase + r;
          const int n = nBase + gc * 8;
          float v[8];
          *(float4*)&v[0] = *(const float4*)&E[r * 64 + gc * 8];
          *(float4*)&v[4] = *(const float4*)&E[r * 64 + gc * 8 + 4];
          if (g.mode == 1) {
            const int bb = token >> 10, sr = token & 1023;
            const int h = n >> 6, d = n & 63;
            const size_t base = (size_t)(bb * 16 + h) * QPL + (size_t)sr * 64 + d;
            pack8 pu, pv;
#pragma unroll
            for (int j = 0; j < 8; ++j) {
              const float qv_ = v[j] + g.bias[n + j];
              pu.u[j] = f2bf(qv_ + g.ub[n + j]);
              pv.u[j] = f2bf(qv_ + g.vb[n + j]);
            }
            *(uint4*)(g.O1 + base) = pu.v;
            *(uint4*)(g.O2 + base) = pv.v;
          } else {  // mode 2 (Ksw, +bias) or 4 (Psw, no bias)
            const int bb = token >> 10, jr = token & 1023;
            const int h = n >> 6, dd = n & 63;
            const int ks = dd >> 5, qk = (dd >> 3) & 3;
            size_t base;
            if (g.mode == 2)
              base = (size_t)(bb * 16 + h) * KPL + (size_t)(jr >> 6) * 4096 +
                     (size_t)((((jr >> 4) & 3) * 2 + ks)) * 512 + (qk * 16 + (jr & 15)) * 8;
            else {
              const int ro = jr + PADLO;
              base = (size_t)(bb * 16 + h) * PPL + (size_t)(ro >> 4) * 1024 +
                     (size_t)ks * 512 + (qk * 16 + (ro & 15)) * 8;
            }
            pack8 pk;
#pragma unroll
            for (int j = 0; j < 8; ++j)
              pk.u[j] = f2bf(v[j] + (g.mode == 2 ? g.bias[n + j] : 0.f));
            *(uint4*)(g.O1 + base) = pk.v;
          }
        }
      }
    }
  }
}

// ---------------------------------------------------------------------------
// Output GEMM (round-2 proven structure): C[4096,1024] = A @ Wout^T + bout.
// ---------------------------------------------------------------------------
__global__ __launch_bounds__(256, 2) void gemm_out(
    const ushort* __restrict__ Ahi, const ushort* __restrict__ Alo,
    const ushort* __restrict__ Bhi, const ushort* __restrict__ Blo,
    const float* __restrict__ bias, float* __restrict__ C)
{
  __shared__ __align__(16) ushort SM[12288];  // 24 KB staging; epilogue 16 KB
  const int tid = threadIdx.x;
  const int wave = tid >> 6, lane = tid & 63;
  const int m16 = lane & 15, quad = lane >> 4;
  const int mw2 = wave & 1, nw2 = wave >> 1;
  const int mt0 = blockIdx.y * 4;
  const int nt0 = blockIdx.x * 8;

  f32x4 acc[2][4];
#pragma unroll
  for (int mf = 0; mf < 2; ++mf)
#pragma unroll
    for (int nf = 0; nf < 4; ++nf) acc[mf][nf] = (f32x4){0.f, 0.f, 0.f, 0.f};

  for (int kb = 0; kb < 32; ++kb) {
    __syncthreads();
    for (int t = wave; t < 24; t += 4) {
      const ushort* g;
      int l;
      if (t < 4)       { g = Ahi + ((size_t)(mt0 + t) * 32 + kb) * 512;      l = t * 512; }
      else if (t < 8)  { g = Alo + ((size_t)(mt0 + t - 4) * 32 + kb) * 512;  l = 2048 + (t - 4) * 512; }
      else if (t < 16) { g = Bhi + ((size_t)(nt0 + t - 8) * 32 + kb) * 512;  l = 4096 + (t - 8) * 512; }
      else             { g = Blo + ((size_t)(nt0 + t - 16) * 32 + kb) * 512; l = 8192 + (t - 16) * 512; }
      __builtin_amdgcn_global_load_lds((gas_t)(g + lane * 8), (las_t)(SM + l), 16, 0, 0);
    }
    __syncthreads();
    short8 ah[2], al[2], bh[4], bl[4];
#pragma unroll
    for (int mf = 0; mf < 2; ++mf) {
      ah[mf] = *(const short8*)(SM + (mw2 * 2 + mf) * 512 + lane * 8);
      al[mf] = *(const short8*)(SM + 2048 + (mw2 * 2 + mf) * 512 + lane * 8);
    }
#pragma unroll
    for (int nf = 0; nf < 4; ++nf) {
      bh[nf] = *(const short8*)(SM + 4096 + (nw2 * 4 + nf) * 512 + lane * 8);
      bl[nf] = *(const short8*)(SM + 8192 + (nw2 * 4 + nf) * 512 + lane * 8);
    }
#pragma unroll
    for (int mf = 0; mf < 2; ++mf)
#pragma unroll
      for (int nf = 0; nf < 4; ++nf) {
        acc[mf][nf] = __builtin_amdgcn_mfma_f32_16x16x32_bf16(ah[mf], bh[nf], acc[mf][nf], 0, 0, 0);
        acc[mf][nf] = __builtin_amdgcn_mfma_f32_16x16x32_bf16(ah[mf], bl[nf], acc[mf][nf], 0, 0, 0);
        acc[mf][nf] = __builtin_amdgcn_mfma_f32_16x16x32_bf16(al[mf], bh[nf], acc[mf][nf], 0, 0, 0);
      }
  }

  const int Mb = blockIdx.y * 64, Nb = blockIdx.x * 128;
  float* const E = (float*)SM;  // [64][64]
#pragma unroll
  for (int c = 0; c < 2; ++c) {
    __syncthreads();
    if (nw2 == c) {
#pragma unroll
      for (int mf = 0; mf < 2; ++mf)
#pragma unroll
        for (int nf = 0; nf < 4; ++nf)
#pragma unroll
          for (int reg = 0; reg < 4; ++reg)
            E[(mw2 * 32 + mf * 16 + quad * 4 + reg) * 64 + nf * 16 + m16] = acc[mf][nf][reg];
    }
    __syncthreads();
#pragma unroll
    for (int q = 0; q < 2; ++q) {
      const int s = tid + 256 * q;
      const int r = s >> 3, g = s & 7;
      const int token = Mb + r;
      const int n = Nb + c * 64 + g * 8;
      float v[8];
      *(float4*)&v[0] = *(const float4*)&E[r * 64 + g * 8];
      *(float4*)&v[4] = *(const float4*)&E[r * 64 + g * 8 + 4];
      float4 o0, o1;
      o0.x = v[0] + bias[n + 0]; o0.y = v[1] + bias[n + 1];
      o0.z = v[2] + bias[n + 2]; o0.w = v[3] + bias[n + 3];
      o1.x = v[4] + bias[n + 4]; o1.y = v[5] + bias[n + 5];
      o1.z = v[6] + bias[n + 6]; o1.w = v[7] + bias[n + 7];
      *(float4*)(C + (size_t)token * 1024 + n) = o0;
      *(float4*)(C + (size_t)token * 1024 + n + 4) = o1;
    }
  }
}

// ---------------------------------------------------------------------------
// len + zero P_sw row r=-1 (ro=1055: block 65, rr=15) per plane of this batch
// ---------------------------------------------------------------------------
__global__ void len_kernel(const int* __restrict__ mask, int* __restrict__ len,
                           ushort* __restrict__ Psw)
{
  const int b = blockIdx.x;
  int cnt = 0;
  for (int i = threadIdx.x; i < S_; i += 256)
    cnt += (mask[(size_t)b * S_ * S_ + (size_t)i * S_] != 0) ? 1 : 0;
  __shared__ int sh[256];
  sh[threadIdx.x] = cnt;
  __syncthreads();
  for (int off = 128; off > 0; off >>= 1) {
    if (threadIdx.x < off) sh[threadIdx.x] += sh[threadIdx.x + off];
    __syncthreads();
  }
  if (threadIdx.x == 0) len[b] = S_ - sh[0];
  for (int idx = threadIdx.x; idx < 16 * 64; idx += 256) {
    const int h = idx >> 6, d = idx & 63;
    Psw[(size_t)(b * 16 + h) * PPL + 65 * 1024 + (d >> 5) * 512 +
        (((d >> 3) & 3) * 16 + 15) * 8 + (d & 7)] = 0;
  }
}

// ---------------------------------------------------------------------------
// MFMA flash attention, 64 q-rows / block, 8 waves (two 32-row halves sharing
// staged K/V and a union P1/P2 window). Round-4 kernel body (verified 265 us
// x3) + NEW: XCD head-pinning block swizzle. Default dispatch puts q-tiles of
// every (b,h) plane on all 8 XCDs (64 planes/XCD, ~30 MB >> 4 MB L2). Remap
// so XCD k owns heads {k, k+8} of all batches: 8 planes/XCD (~4.5 MB, L2-fit),
// exactly 128 blocks/XCD, batches evenly spread (variable-L balanced).
// ---------------------------------------------------------------------------
__global__ __launch_bounds__(512, 4) void attn_mfma2(
    const ushort* __restrict__ Qu, const ushort* __restrict__ Qv,
    const ushort* __restrict__ Ksw, const ushort* __restrict__ Vsw,
    const ushort* __restrict__ Psw, const int* __restrict__ len,
    float* __restrict__ CTX)
{
  __shared__ __align__(16) ushort SMEM[26624];   // 53248 B
  __shared__ float mrow[64], lrow[64], arow[64];

  ushort* const Ks_  = SMEM;            // 8 slots (4096 us)
  ushort* const Vts_ = SMEM + 4096;     // 8 slots
  ushort* const P1s_ = SMEM + 8192;     // 18 slots (9216 us) union window
  ushort* const P2s_ = SMEM + 17408;    // 18 slots
  float*  const sc   = (float*)(SMEM + 8192);   // 64x68 f32 = 17408 B (in P1s)
  ushort* const Pb   = SMEM + 17408;            // 64x72 us  =  9216 B (in P2s)

  const int tid  = threadIdx.x;
  const int wave = tid >> 6, lane = tid & 63;
  const int hw   = wave >> 2, w4 = wave & 3;   // half index, wave-within-half
  const int m16  = lane & 15, quad = lane >> 4;
  const int mw   = w4 & 1,  nw   = w4 >> 1;
  const int koff0 = quad * 8;

  // XCD head-pinning swizzle: lid -> (qt, h, b) with h mod 8 == XCD (lid&7).
  const int lid = blockIdx.x + 16 * blockIdx.y + 256 * blockIdx.z;  // grid (16,16,4)
  const int xcd = lid & 7;
  const int idx = lid >> 3;              // [0,128) within XCD
  const int h   = xcd + 8 * (idx & 1);
  const int b   = (idx >> 1) & 3;
  const int qt  = idx >> 3;              // [0,16)

  const int base = qt * 64;
  const int i0 = base + hw * 32;
  const int ph = b * 16 + h;
  const int L  = len[b];
  const size_t gb = ((size_t)b * S_) * D_ + h * DH_;

  if (base >= L) {
    for (int idx2 = tid; idx2 < 64 * 64; idx2 += 512) {
      const int r = idx2 >> 6, d = idx2 & 63;
      CTX[gb + (size_t)(base + r) * D_ + d] = 0.f;
    }
    return;
  }
  const bool active = (i0 < L);

  const ushort* quP = Qu + (size_t)ph * QPL;
  const ushort* qvP = Qv + (size_t)ph * QPL;
  short8 qufr[2][2], qvfr[2][2][2];
#pragma unroll
  for (int Mt = 0; Mt < 2; ++Mt)
#pragma unroll
    for (int ks = 0; ks < 2; ++ks) {
      qufr[Mt][ks] = *(const short8*)(quP + (size_t)(i0 + 16 * Mt + m16) * 64 + ks * 32 + koff0);
#pragma unroll
      for (int off = 0; off < 2; ++off)
        qvfr[off][Mt][ks] =
            *(const short8*)(qvP + (size_t)(i0 + off + 16 * Mt + m16) * 64 + ks * 32 + koff0);
    }

  if (tid < 64) { mrow[tid] = -3.0e38f; lrow[tid] = 0.f; arow[tid] = 0.f; }

  f32x4 ctx0 = {0.f, 0.f, 0.f, 0.f}, ctx1 = {0.f, 0.f, 0.f, 0.f};

  const ushort* ksP = Ksw + (size_t)ph * KPL;
  const ushort* vsP = Vsw + (size_t)ph * VPL;
  const ushort* psP = Psw + (size_t)ph * PPL;

  for (int j0 = 0; j0 < L; j0 += 64) {
    __syncthreads();

    const int jt = j0 >> 6;
    const int A1 = L - 32 - i0 + j0, A2 = j0 - i0 - 33;
    const int ro1 = A1 + PADLO, ro2 = A2 + PADLO;
    const int rb1 = ro1 >> 4, rb2 = ro2 >> 4;
    const int d1 = ro1 & 15, d2 = ro2 & 15;
    const int rb1lo = (L - 64 - base + j0 + PADLO) >> 4;
    const int rb2lo = (j0 - base - 65 + PADLO) >> 4;
    const ushort* P1h = P1s_ + ((rb1 - rb1lo) << 10);
    const ushort* P2h = P2s_ + ((rb2 - rb2lo) << 10);

    {
      const ushort* kgo = ksP + (size_t)jt * 4096;
      const ushort* vgo = vsP + (size_t)jt * 4096;
      const ushort* p1o = psP + (size_t)rb1lo * 1024;
      const ushort* p2o = psP + (size_t)rb2lo * 1024;
      for (int t = wave; t < 52; t += 8) {
        const ushort* g;
        int l;
        if (t < 8)       { g = kgo + t * 512;        l = t * 512; }
        else if (t < 16) { g = vgo + (t - 8) * 512;  l = 4096 + (t - 8) * 512; }
        else if (t < 34) { g = p1o + (t - 16) * 512; l = 8192 + (t - 16) * 512; }
        else             { g = p2o + (t - 34) * 512; l = 17408 + (t - 34) * 512; }
        __builtin_amdgcn_global_load_lds((gas_t)(g + lane * 8), (las_t)(SMEM + l), 16, 0, 0);
      }
    }
    __syncthreads();

    const int jrem = L - j0;
    const int jmax = (jrem < 64) ? jrem : 64;
    const int cthr = 31 + i0 - j0;

    f32x4 av[9];
#pragma unroll
    for (int t = 0; t < 9; ++t) {
      const int id = w4 + 4 * t;
      f32x4 a = {0.f, 0.f, 0.f, 0.f};
      if (active) {
        if (id < 8) {
          const int Mt = id & 1, Nt = id >> 1;
          if (16 * Nt < jmax) {
            const ushort* bp = Ks_ + (Nt * 2) * 512 + lane * 8;
            a = __builtin_amdgcn_mfma_f32_16x16x32_bf16(qufr[Mt][0], *(const short8*)bp, a, 0, 0, 0);
            a = __builtin_amdgcn_mfma_f32_16x16x32_bf16(qufr[Mt][1], *(const short8*)(bp + 512), a, 0, 0, 0);
          }
        } else if (id < 22) {
          const int e = id - 8, Mt = e & 1, Ntp = e >> 1;
          const int sm = 16 * (Ntp + Mt);
          if (sm >= d1 + 1 && sm <= jmax + d1 + 30 && 16 * Ntp - d1 <= cthr) {
            const ushort* bp = P1h + (Ntp * 2) * 512 + lane * 8;
            a = __builtin_amdgcn_mfma_f32_16x16x32_bf16(qvfr[0][Mt][0], *(const short8*)bp, a, 0, 0, 0);
            a = __builtin_amdgcn_mfma_f32_16x16x32_bf16(qvfr[0][Mt][1], *(const short8*)(bp + 512), a, 0, 0, 0);
          }
        } else {
          const int e = id - 22, Mt = e & 1, Ntp = e >> 1;
          const int sm = 16 * (Ntp + Mt);
          if (sm >= d2 + 1 && sm <= jmax + d2 + 30 && 16 * Ntp + 15 - d2 > cthr) {
            const ushort* bp = P2h + (Ntp * 2) * 512 + lane * 8;
            a = __builtin_amdgcn_mfma_f32_16x16x32_bf16(qvfr[1][Mt][0], *(const short8*)bp, a, 0, 0, 0);
            a = __builtin_amdgcn_mfma_f32_16x16x32_bf16(qvfr[1][Mt][1], *(const short8*)(bp + 512), a, 0, 0, 0);
          }
        }
      }
      av[t] = a;
    }
    __syncthreads();

#pragma unroll
    for (int t = 0; t < 2; ++t) {   // only t=0,1 can have id<8
      const int id = w4 + 4 * t;
      if (id < 8) {
        const int Mt = id & 1, Nt = id >> 1;
        if (16 * Nt < jmax) {
#pragma unroll
          for (int reg = 0; reg < 4; ++reg)
            sc[(hw * 32 + 16 * Mt + quad * 4 + reg) * 68 + 16 * Nt + m16] =
                active ? av[t][reg] : 0.f;
        }
      }
    }
    __syncthreads();

    if (active) {
#pragma unroll
      for (int t = 0; t < 9; ++t) {
        const int id = w4 + 4 * t;
        if (id >= 8) {
          const bool isG2 = id >= 22;
          const int e = id - (isG2 ? 22 : 8), Mt = e & 1, Ntp = e >> 1;
          const int dl = isG2 ? d2 : d1;
          const int sm = 16 * (Ntp + Mt);
          const bool use = sm >= dl + 1 && sm <= jmax + dl + 30 &&
                           (isG2 ? (16 * Ntp + 15 - dl > cthr) : (16 * Ntp - dl <= cthr));
          if (use) {
            const int c = 16 * Ntp + m16 - dl;
            const bool sel = isG2 ? (c > cthr) : (c <= cthr);
            if (sel) {
#pragma unroll
              for (int reg = 0; reg < 4; ++reg) {
                const int il = 16 * Mt + quad * 4 + reg;
                const int jl = c - 31 + il;
                if (jl >= 0 && jl < 64) sc[(hw * 32 + il) * 68 + jl] += av[t][reg];
              }
            }
          }
        }
      }
    }
    __syncthreads();

    {
      const int row = tid >> 3, t8 = tid & 7, jb = t8 * 8;
      const float* sr = sc + row * 68 + jb;
      float mx = -3.0e38f;
#pragma unroll
      for (int q = 0; q < 8; ++q)
        if (jb + q < jmax) mx = fmaxf(mx, sr[q]);
#pragma unroll
      for (int off = 1; off < 8; off <<= 1)
        mx = fmaxf(mx, __shfl_xor(mx, off, 64));
      if (t8 == 0) {
        const float mo = mrow[row];
        const float mn = fmaxf(mo, mx);
        arow[row] = __expf((mo - mn) * OOS);
        mrow[row] = mn;
      }
    }
    __syncthreads();
    {
      const int row = tid >> 3, t8 = tid & 7, jb = t8 * 8;
      const float m = mrow[row];
      const float* sr = sc + row * 68 + jb;
      float e[8], s = 0.f;
#pragma unroll
      for (int q = 0; q < 8; ++q) {
        float v = 0.f;
        if (jb + q < jmax) v = __expf((sr[q] - m) * OOS);
        e[q] = v;
        s += v;
      }
      ushort4 u0, u1;
      u0.x = f2bf(e[0]); u0.y = f2bf(e[1]); u0.z = f2bf(e[2]); u0.w = f2bf(e[3]);
      u1.x = f2bf(e[4]); u1.y = f2bf(e[5]); u1.z = f2bf(e[6]); u1.w = f2bf(e[7]);
      *(ushort4*)&Pb[row * 72 + jb] = u0;
      *(ushort4*)&Pb[row * 72 + jb + 4] = u1;
#pragma unroll
      for (int off = 1; off < 8; off <<= 1) s += __shfl_xor(s, off, 64);
      if (t8 == 0) lrow[row] = lrow[row] * arow[row] + s;
    }
    __syncthreads();

    if (active) {
      float al[4];
#pragma unroll
      for (int reg = 0; reg < 4; ++reg) al[reg] = arow[hw * 32 + 16 * mw + quad * 4 + reg];
#pragma unroll
      for (int reg = 0; reg < 4; ++reg) { ctx0[reg] *= al[reg]; ctx1[reg] *= al[reg]; }
      const ushort* ap = Pb + (hw * 32 + 16 * mw + m16) * 72;
#pragma unroll
      for (int ksj = 0; ksj < 2; ++ksj) {
        const short8 a = *(const short8*)(ap + ksj * 32 + koff0);
        ctx0 = __builtin_amdgcn_mfma_f32_16x16x32_bf16(
            a, *(const short8*)(Vts_ + ((nw * 2) * 2 + ksj) * 512 + lane * 8), ctx0, 0, 0, 0);
        ctx1 = __builtin_amdgcn_mfma_f32_16x16x32_bf16(
            a, *(const short8*)(Vts_ + ((nw * 2 + 1) * 2 + ksj) * 512 + lane * 8), ctx1, 0, 0, 0);
      }
    }
  }

#pragma unroll
  for (int reg = 0; reg < 4; ++reg) {
    const int il = 16 * mw + quad * 4 + reg;
    const int gi = i0 + il;
    const float inv = (active && gi < L) ? (1.f / lrow[hw * 32 + il]) : 0.f;
    CTX[gb + (size_t)gi * D_ + nw * 32 + m16]      = ctx0[reg] * inv;
    CTX[gb + (size_t)gi * D_ + nw * 32 + 16 + m16] = ctx1[reg] * inv;
  }
}

// ---------------------------------------------------------------------------
extern "C" void kernel_launch(void* const* d_in, const int* in_sizes, int n_in,
                              void* d_out, int out_size, void* d_ws, size_t ws_size,
                              hipStream_t stream)
{
  (void)in_sizes; (void)n_in; (void)out_size;
  const float* query = (const float*)d_in[0];
  const float* key   = (const float*)d_in[1];
  const float* value = (const float*)d_in[2];
  const float* pos   = (const float*)d_in[3];
  const float* Wq    = (const float*)d_in[4];
  const float* bq    = (const float*)d_in[5];
  const float* Wk    = (const float*)d_in[6];
  const float* bk    = (const float*)d_in[7];
  const float* Wv    = (const float*)d_in[8];
  const float* bv    = (const float*)d_in[9];
  const float* Wpos  = (const float*)d_in[10];
  const float* ub    = (const float*)d_in[11];
  const float* vb    = (const float*)d_in[12];
  const float* Wout  = (const float*)d_in[13];
  const float* bout  = (const float*)d_in[14];
  const int*   mask  = (const int*)d_in[15];

  char* cur = (char*)d_ws;
  auto take = [&](size_t bytes) {
    char* p = cur;
    cur += (bytes + 255) & ~(size_t)255;
    return p;
  };
  float*  CTX = (float*)take((size_t)4096 * 1024 * 4);
  ushort* Qu  = (ushort*)take((size_t)64 * QPL * 2);
  ushort* Qv  = (ushort*)take((size_t)64 * QPL * 2);
  ushort* Ksw = (ushort*)take((size_t)64 * KPL * 2);
  ushort* Vsw = (ushort*)take((size_t)64 * VPL * 2);
  ushort* Psw = (ushort*)take((size_t)64 * PPL * 2);
  ushort* Ah[4], *Al[4];
  for (int i = 0; i < 4; ++i) {
    Ah[i] = (ushort*)take((size_t)APL_SW * 2);
    Al[i] = (ushort*)take((size_t)APL_SW * 2);
  }
  ushort* Wh[5], *Wl[5];
  for (int i = 0; i < 5; ++i) {
    Wh[i] = (ushort*)take((size_t)WPL_SW * 2);
    Wl[i] = (ushort*)take((size_t)WPL_SW * 2);
  }
  int* len = (int*)take(256);
  // CTX hi/lo alias the (then-dead) query activation planes
  ushort* Ch = Ah[0];
  ushort* Cl = Al[0];
  if (ws_size < (size_t)(cur - (char*)d_ws)) return;

  len_kernel<<<dim3(B_), dim3(256), 0, stream>>>(mask, len, Psw);

  // fp32 -> swizzled hi/lo bf16 conversions
  {
    ConvArgs a;
    a.d[0] = {query, Ah[0], Al[0]};
    a.d[1] = {key,   Ah[1], Al[1]};
    a.d[2] = {value, Ah[2], Al[2]};
    a.d[3] = {pos,   Ah[3], Al[3]};
    a.d[4] = {query, Ah[0], Al[0]};  // unused
    conv_split<<<dim3(256, 4), dim3(256), 0, stream>>>(a);
    ConvArgs w;
    w.d[0] = {Wq,   Wh[0], Wl[0]};
    w.d[1] = {Wk,   Wh[1], Wl[1]};
    w.d[2] = {Wv,   Wh[2], Wl[2]};
    w.d[3] = {Wpos, Wh[3], Wl[3]};
    w.d[4] = {Wout, Wh[4], Wl[4]};
    conv_split<<<dim3(64, 5), dim3(256), 0, stream>>>(w);
  }

  // fused QKVP projections: z = {Q->Qu/Qv, K->Ksw, V->Vsw, P->Psw}
  {
    GemmArgs ga;
    ga.g[0] = {Ah[0], Al[0], Wh[0], Wl[0], bq, Qu, Qv, ub, vb, 1, 0};
    ga.g[1] = {Ah[1], Al[1], Wh[1], Wl[1], bk, Ksw, nullptr, nullptr, nullptr, 2, 0};
    ga.g[2] = {Ah[2], Al[2], Wh[2], Wl[2], bv, Vsw, nullptr, nullptr, nullptr, 3, 0};
    ga.g[3] = {Ah[3], Al[3], Wh[3], Wl[3], nullptr, Psw, nullptr, nullptr, nullptr, 4, 0};
    gemm_fused<<<dim3(8, 32, 4), dim3(256), 0, stream>>>(ga);
  }

  attn_mfma2<<<dim3(S_ / 64, H_, B_), dim3(512), 0, stream>>>(
      Qu, Qv, Ksw, Vsw, Psw, len, CTX);

  {
    ConvArgs c;
    c.d[0] = {CTX, Ch, Cl};
    c.d[1] = c.d[0]; c.d[2] = c.d[0]; c.d[3] = c.d[0]; c.d[4] = c.d[0];
    conv_split<<<dim3(256, 1), dim3(256), 0, stream>>>(c);
  }

  gemm_out<<<dim3(8, 64), dim3(256), 0, stream>>>(Ch, Cl, Wh[4], Wl[4], bout,
                                                  (float*)d_out);
}